// Round 1
// baseline (4307.819 us; speedup 1.0000x reference)
//
#include <hip/hip_runtime.h>
#include <hip/hip_bf16.h>
#include <math.h>

// Problem constants
#define B_ 2
#define S_ 2048
#define D_ 1024
#define H_ 16
#define DK_ 64
#define DV_ 64
#define TEMP_ 8.0f
#define EPS_ 1e-6f

// ---------------- block reduce helpers (256 threads, 4 waves) ----------------
__device__ __forceinline__ float blockReduceMax(float v, float* red) {
#pragma unroll
    for (int o = 32; o > 0; o >>= 1) v = fmaxf(v, __shfl_xor(v, o));
    __syncthreads();
    if ((threadIdx.x & 63) == 0) red[threadIdx.x >> 6] = v;
    __syncthreads();
    return fmaxf(fmaxf(red[0], red[1]), fmaxf(red[2], red[3]));
}

__device__ __forceinline__ float blockReduceSum(float v, float* red) {
#pragma unroll
    for (int o = 32; o > 0; o >>= 1) v += __shfl_xor(v, o);
    __syncthreads();
    if ((threadIdx.x & 63) == 0) red[threadIdx.x >> 6] = v;
    __syncthreads();
    return red[0] + red[1] + red[2] + red[3];
}

// ---------------- fp32 SGEMM: C[M,N] = A[M,K] @ W[K,N] (+ res) ----------------
// 128x128 tile, BK=8, 256 threads, 8x8 per thread.
__global__ __launch_bounds__(256) void gemm_f32(const float* __restrict__ A,
                                                const float* __restrict__ W,
                                                float* __restrict__ C,
                                                const float* __restrict__ res,
                                                int M, int N, int K) {
    __shared__ float As[8][132];   // transposed, padded (16B-aligned rows per ty*8)
    __shared__ float Bs[8][128];

    const int t  = threadIdx.x;
    const int tx = t & 15;         // 0..15 -> col group
    const int ty = t >> 4;         // 0..15 -> row group
    const int bm = blockIdx.y * 128;
    const int bn = blockIdx.x * 128;

    const int ar = t >> 1;         // 0..127
    const int ac = (t & 1) * 4;    // 0 or 4
    const int br = t >> 5;         // 0..7
    const int bc = (t & 31) * 4;   // 0..124

    float acc[8][8];
#pragma unroll
    for (int i = 0; i < 8; ++i)
#pragma unroll
        for (int j = 0; j < 8; ++j) acc[i][j] = 0.f;

    for (int k0 = 0; k0 < K; k0 += 8) {
        float4 a4 = *(const float4*)&A[(size_t)(bm + ar) * K + k0 + ac];
        As[ac + 0][ar] = a4.x;
        As[ac + 1][ar] = a4.y;
        As[ac + 2][ar] = a4.z;
        As[ac + 3][ar] = a4.w;
        float4 b4 = *(const float4*)&W[(size_t)(k0 + br) * N + bn + bc];
        *(float4*)&Bs[br][bc] = b4;
        __syncthreads();

#pragma unroll
        for (int kk = 0; kk < 8; ++kk) {
            float4 a0 = *(const float4*)&As[kk][ty * 8];
            float4 a1 = *(const float4*)&As[kk][ty * 8 + 4];
            float4 b0 = *(const float4*)&Bs[kk][tx * 8];
            float4 b1 = *(const float4*)&Bs[kk][tx * 8 + 4];
            float a[8] = {a0.x, a0.y, a0.z, a0.w, a1.x, a1.y, a1.z, a1.w};
            float b[8] = {b0.x, b0.y, b0.z, b0.w, b1.x, b1.y, b1.z, b1.w};
#pragma unroll
            for (int i = 0; i < 8; ++i)
#pragma unroll
                for (int j = 0; j < 8; ++j) acc[i][j] += a[i] * b[j];
        }
        __syncthreads();
    }

#pragma unroll
    for (int i = 0; i < 8; ++i) {
        const size_t row = (size_t)(bm + ty * 8 + i);
        float4 o0, o1;
        o0.x = acc[i][0]; o0.y = acc[i][1]; o0.z = acc[i][2]; o0.w = acc[i][3];
        o1.x = acc[i][4]; o1.y = acc[i][5]; o1.z = acc[i][6]; o1.w = acc[i][7];
        if (res) {
            float4 r0 = *(const float4*)&res[row * N + bn + tx * 8];
            float4 r1 = *(const float4*)&res[row * N + bn + tx * 8 + 4];
            o0.x += r0.x; o0.y += r0.y; o0.z += r0.z; o0.w += r0.w;
            o1.x += r1.x; o1.y += r1.y; o1.z += r1.z; o1.w += r1.w;
        }
        *(float4*)&C[row * N + bn + tx * 8]     = o0;
        *(float4*)&C[row * N + bn + tx * 8 + 4] = o1;
    }
}

// ---------------- attention: scores + softmax + attn-write + PV ----------------
// One block handles QT=8 query rows of one (b,h). 256 threads.
#define QT 8
__global__ __launch_bounds__(256) void attn_kernel(const float* __restrict__ qp,
                                                   const float* __restrict__ kp,
                                                   const float* __restrict__ vp,
                                                   const int* __restrict__ mask,
                                                   float* __restrict__ attn_out,
                                                   float* __restrict__ ctx) {
    __shared__ float qs[QT][64];
    __shared__ float ps[QT][2048];
    __shared__ float part[4][QT][64];
    __shared__ float red[4];
    __shared__ float invs[QT];

    const int t  = threadIdx.x;
    const int q0 = blockIdx.x * QT;
    const int h  = blockIdx.y;
    const int b  = blockIdx.z;
    const int bS = b * S_;

    // load q rows (pre-scaled by 1/TEMP)
    for (int i = t; i < QT * 64; i += 256) {
        int r = i >> 6, dk = i & 63;
        qs[r][dk] = qp[(size_t)(bS + q0 + r) * D_ + h * 64 + dk] * (1.0f / TEMP_);
    }
    __syncthreads();

    // phase 1: scores -> ps
    for (int c = 0; c < 8; ++c) {
        const int ki = c * 256 + t;
        const float4* k4 = (const float4*)&kp[(size_t)(bS + ki) * D_ + h * 64];
        float dot[QT];
#pragma unroll
        for (int r = 0; r < QT; ++r) dot[r] = 0.f;
#pragma unroll
        for (int j = 0; j < 16; ++j) {
            float4 kv = k4[j];
#pragma unroll
            for (int r = 0; r < QT; ++r) {
                float4 qv = *(const float4*)&qs[r][j * 4];
                dot[r] += qv.x * kv.x + qv.y * kv.y + qv.z * kv.z + qv.w * kv.w;
            }
        }
#pragma unroll
        for (int r = 0; r < QT; ++r) {
            int m = mask[(size_t)(bS + q0 + r) * S_ + ki];
            ps[r][ki] = (m == 0) ? -1e9f : dot[r];
        }
    }
    __syncthreads();

    // phase 2: per-row softmax, write normalized attn, keep e in ps
    for (int r = 0; r < QT; ++r) {
        float lm = -1e30f;
#pragma unroll
        for (int c = 0; c < 8; ++c) lm = fmaxf(lm, ps[r][c * 256 + t]);
        const float M = blockReduceMax(lm, red);
        float e[8], ls = 0.f;
#pragma unroll
        for (int c = 0; c < 8; ++c) {
            e[c] = __expf(ps[r][c * 256 + t] - M);
            ls += e[c];
        }
        const float Ssum = blockReduceSum(ls, red);
        const float is = 1.0f / Ssum;
        const size_t arow = ((size_t)((b * H_ + h) * S_) + q0 + r) * S_;
#pragma unroll
        for (int c = 0; c < 8; ++c) {
            attn_out[arow + c * 256 + t] = e[c] * is;
            ps[r][c * 256 + t] = e[c];
        }
        if (t == 0) invs[r] = is;
    }
    __syncthreads();

    // phase 3: PV. dv = t&63, k-chunk = t>>6 (4 chunks x 512)
    const int dv = t & 63;
    const int cg = t >> 6;
    float acc[QT];
#pragma unroll
    for (int r = 0; r < QT; ++r) acc[r] = 0.f;
    for (int i4 = 0; i4 < 512; i4 += 4) {
        const int ki = cg * 512 + i4;
        const float v0 = vp[(size_t)(bS + ki + 0) * D_ + h * 64 + dv];
        const float v1 = vp[(size_t)(bS + ki + 1) * D_ + h * 64 + dv];
        const float v2 = vp[(size_t)(bS + ki + 2) * D_ + h * 64 + dv];
        const float v3 = vp[(size_t)(bS + ki + 3) * D_ + h * 64 + dv];
#pragma unroll
        for (int r = 0; r < QT; ++r) {
            float4 p = *(const float4*)&ps[r][ki];
            acc[r] += p.x * v0 + p.y * v1 + p.z * v2 + p.w * v3;
        }
    }
#pragma unroll
    for (int r = 0; r < QT; ++r) part[cg][r][dv] = acc[r];
    __syncthreads();
    for (int idx = t; idx < QT * 64; idx += 256) {
        int r = idx >> 6, d2 = idx & 63;
        float o = (part[0][r][d2] + part[1][r][d2] + part[2][r][d2] + part[3][r][d2]) * invs[r];
        ctx[(size_t)(bS + q0 + r) * D_ + h * 64 + d2] = o;
    }
}

// ---------------- LayerNorm (in-place on x region of d_out) ----------------
__global__ __launch_bounds__(256) void ln_kernel(float* __restrict__ x,
                                                 const float* __restrict__ gamma,
                                                 const float* __restrict__ beta) {
    __shared__ float red[4];
    const int t = threadIdx.x;
    float* xr = x + (size_t)blockIdx.x * D_;

    float4 xv = ((const float4*)xr)[t];
    float s = xv.x + xv.y + xv.z + xv.w;
    s = blockReduceSum(s, red);
    const float mu = s * (1.0f / (float)D_);

    float dx0 = xv.x - mu, dx1 = xv.y - mu, dx2 = xv.z - mu, dx3 = xv.w - mu;
    float sq = dx0 * dx0 + dx1 * dx1 + dx2 * dx2 + dx3 * dx3;
    sq = blockReduceSum(sq, red);
    const float var = sq * (1.0f / (float)D_);
    const float rstd = rsqrtf(var + EPS_);

    float4 g  = ((const float4*)gamma)[t];
    float4 be = ((const float4*)beta)[t];
    float4 o;
    o.x = dx0 * rstd * g.x + be.x;
    o.y = dx1 * rstd * g.y + be.y;
    o.z = dx2 * rstd * g.z + be.z;
    o.w = dx3 * rstd * g.w + be.w;
    ((float4*)xr)[t] = o;
}

extern "C" void kernel_launch(void* const* d_in, const int* in_sizes, int n_in,
                              void* d_out, int out_size, void* d_ws, size_t ws_size,
                              hipStream_t stream) {
    const float* q     = (const float*)d_in[0];
    const float* k     = (const float*)d_in[1];
    const float* v     = (const float*)d_in[2];
    const int*   mask  = (const int*)d_in[3];
    const float* Wq    = (const float*)d_in[4];
    const float* Wk    = (const float*)d_in[5];
    const float* Wv    = (const float*)d_in[6];
    const float* Wo    = (const float*)d_in[7];
    const float* gamma = (const float*)d_in[8];
    const float* beta  = (const float*)d_in[9];

    float* out_x    = (float*)d_out;                                   // [B,S,D]
    float* out_attn = (float*)d_out + (size_t)B_ * S_ * D_;            // [B,H,S,S]

    const size_t NROW = (size_t)B_ * S_;  // 4096
    float* qp  = (float*)d_ws;            // [NROW, 1024]
    float* kp  = qp + NROW * D_;
    float* vp  = kp + NROW * D_;
    float* ctx = vp + NROW * D_;

    const int M = (int)NROW, N = H_ * DK_, K = D_;

    dim3 gemm_grid(N / 128, M / 128);
    gemm_f32<<<gemm_grid, 256, 0, stream>>>(q, Wq, qp, nullptr, M, N, K);
    gemm_f32<<<gemm_grid, 256, 0, stream>>>(k, Wk, kp, nullptr, M, N, K);
    gemm_f32<<<gemm_grid, 256, 0, stream>>>(v, Wv, vp, nullptr, M, N, K);

    dim3 attn_grid(S_ / QT, H_, B_);
    attn_kernel<<<attn_grid, 256, 0, stream>>>(qp, kp, vp, mask, out_attn, ctx);

    gemm_f32<<<gemm_grid, 256, 0, stream>>>(ctx, Wo, out_x, q, M, D_, H_ * DV_);

    ln_kernel<<<NROW, 256, 0, stream>>>(out_x, gamma, beta);
}